// Round 5
// baseline (1413.981 us; speedup 1.0000x reference)
//
#include <hip/hip_runtime.h>

// Fused SIREN INR round 5. Lessons: weight tile loaded ONCE per layer per
// wave (r2/r4 regressions), >=32 MFMAs per k-step (r2/r4), chunk-major LDS
// (r3, conflicts -80%). New vs r3: WG = 256 thr / 4 waves / TOK=64, wave =
// 128 feats x 64 tok (acc 8x4, same 128 f32), LDS 64KB -> TWO WGs per CU
// with INDEPENDENT barriers. When WG0 is in its epilogue/barrier window,
// WG1's k-loop keeps the matrix pipe fed (cross-WG phase overlap — the
// overlap r4 failed to get intra-wave). Per-CU L2 weight traffic 2x but
// ~13 B/cyc/CU vs ~56 available; per-CU LDS b-reads halve.

#define L_TOTAL 262144
#define TOK 64
#define THREADS 256
#define C_SC 4.77464829275686f  // 30/(2*pi)

typedef _Float16 f16x8 __attribute__((ext_vector_type(8)));
typedef _Float16 f16x4 __attribute__((ext_vector_type(4)));
typedef float    f32x4 __attribute__((ext_vector_type(4)));

#define N1 (512 * 256)                 // W_first elems
#define N2 (N1 + 5 * 512 * 512)        // + W_hidden
#define N3 (N2 + 16 * 512)             // + W_out padded to 16 rows
#define NBIAS 3072                     // 512 first + 5*512 hidden (pre-scaled)

__global__ void convert_weights(const float* __restrict__ Wf,
                                const float* __restrict__ Wh,
                                const float* __restrict__ Wo,
                                const float* __restrict__ bf,
                                const float* __restrict__ bh,
                                _Float16* __restrict__ o,
                                float* __restrict__ biasC) {
  int i = blockIdx.x * blockDim.x + threadIdx.x;
  if (i < N3) {
    float v;
    if (i < N1) {
      v = Wf[i];
    } else if (i < N2) {
      v = Wh[i - N1];
    } else {
      int r = (i - N2) >> 9, c = (i - N2) & 511;
      v = (r < 3) ? Wo[r * 512 + c] : 0.0f;
    }
    o[i] = (_Float16)v;
  } else if (i < N3 + NBIAS) {
    int j = i - N3;
    biasC[j] = (j < 512 ? bf[j] : bh[j - 512]) * C_SC;
  }
}

// h LDS layout: elem addr = (chunk*64 + token)*8 + (f&7), chunk = f>>3.
// b-frag ds_read_b128 addr16B = chunk*64 + token: lanes linear in token ->
// 8 consecutive lanes span all 32 banks -> conflict-free.
__device__ __forceinline__ int h_elem(int chunk, int token) {
  return (chunk * 64 + token) * 8;
}

// One sine layer: h <- sin(30*(W h + b)). M=512 (4 waves x 128 feats),
// N=64 tokens (4 ntiles), K templated (256 first / 512 hidden).
template <int K>
__device__ __forceinline__ void sine_layer(const _Float16* __restrict__ W,
                                           const float* __restrict__ biasC,
                                           _Float16* hb, int lr, int lg,
                                           int m0) {
  constexpr int KS = K / 32;
  f32x4 acc[8][4];
#pragma unroll
  for (int mt = 0; mt < 8; ++mt)
#pragma unroll
    for (int nt = 0; nt < 4; ++nt)
      acc[mt][nt] = (f32x4){0.f, 0.f, 0.f, 0.f};

  // per-mt weight-row base (lane-constant in k; ks adds immediate offset)
  const _Float16* wrow[8];
#pragma unroll
  for (int mt = 0; mt < 8; ++mt)
    wrow[mt] = &W[(m0 + mt * 16 + lr) * K + lg * 8];

  f16x8 a[2][8], b[4];
#pragma unroll
  for (int mt = 0; mt < 8; ++mt) a[0][mt] = *(const f16x8*)(wrow[mt]);

#pragma unroll
  for (int ks = 0; ks < KS; ++ks) {
    const int cur = ks & 1;
#pragma unroll
    for (int nt = 0; nt < 4; ++nt)
      b[nt] = *(const f16x8*)&hb[h_elem(ks * 4 + lg, nt * 16 + lr)];
    if (ks + 1 < KS) {  // prefetch next k-step's weight frags under MFMAs
#pragma unroll
      for (int mt = 0; mt < 8; ++mt)
        a[cur ^ 1][mt] = *(const f16x8*)(wrow[mt] + (ks + 1) * 32);
    }
#pragma unroll
    for (int mt = 0; mt < 8; ++mt)
#pragma unroll
      for (int nt = 0; nt < 4; ++nt)
        acc[mt][nt] = __builtin_amdgcn_mfma_f32_16x16x32_f16(
            a[cur][mt], b[nt], acc[mt][nt], 0, 0, 0);
  }
  __syncthreads();  // all reads of hb done before overwrite

#pragma unroll
  for (int mt = 0; mt < 8; ++mt) {
    const int ob = m0 + mt * 16 + lg * 4;  // 4 consecutive out-features
    const f32x4 bb = *(const f32x4*)&biasC[ob];
    const int wbase = (ob >> 3) * 64 * 8 + (ob & 7);
#pragma unroll
    for (int nt = 0; nt < 4; ++nt) {
      f16x4 hv;
#pragma unroll
      for (int r = 0; r < 4; ++r) {
        float pre = fmaf(acc[mt][nt][r], C_SC, bb[r]);  // revolutions
        hv[r] = (_Float16)__builtin_amdgcn_sinf(__builtin_amdgcn_fractf(pre));
      }
      *(f16x4*)&hb[wbase + (nt * 16 + lr) * 8] = hv;
    }
  }
  __syncthreads();
}

__global__ __launch_bounds__(THREADS, 2) void siren_kernel(
    const float* __restrict__ coords, const float* __restrict__ bff,
    const float* __restrict__ biasC, const float* __restrict__ b_out,
    const _Float16* __restrict__ wf, const _Float16* __restrict__ wh,
    const _Float16* __restrict__ wo, float* __restrict__ out) {
  extern __shared__ _Float16 hb[];  // chunk-major: [64 chunks][64 tok][8]
  const int tid = threadIdx.x;
  const int t0 = blockIdx.x * TOK;

  // ---- Fourier features: chunks q*4+cb (sin), 16+q*4+cb (cos) ----
  {
    const int t = tid & 63;    // token (wave = 64 consecutive tokens)
    const int q = tid >> 6;    // feature octant: proj j in [q*32, q*32+32)
    const float c0 = coords[(t0 + t) * 3 + 0];
    const float c1 = coords[(t0 + t) * 3 + 1];
    const float c2 = coords[(t0 + t) * 3 + 2];
#pragma unroll
    for (int cb = 0; cb < 4; ++cb) {
      f16x8 sv, cv;
#pragma unroll
      for (int e = 0; e < 8; ++e) {
        const int j = q * 32 + cb * 8 + e;
        float r = fmaf(c0, bff[j], fmaf(c1, bff[128 + j], c2 * bff[256 + j]));
        float fr = __builtin_amdgcn_fractf(r);
        sv[e] = (_Float16)__builtin_amdgcn_sinf(fr);
        cv[e] = (_Float16)__builtin_amdgcn_cosf(fr);
      }
      *(f16x8*)&hb[h_elem(q * 4 + cb, t)] = sv;        // lane-linear store
      *(f16x8*)&hb[h_elem(16 + q * 4 + cb, t)] = cv;
    }
  }
  __syncthreads();

  const int lane = tid & 63;
  const int lr = lane & 15;   // A: weight row / B: token / C: token col
  const int lg = lane >> 4;   // k-group for frags, row-group for C
  const int m0 = (tid >> 6) * 128;  // wave's 128-feature output slice

  sine_layer<256>(wf, biasC, hb, lr, lg, m0);
#pragma unroll 1
  for (int l = 0; l < 5; ++l)
    sine_layer<512>(wh + l * (512 * 512), biasC + 512 + l * 512, hb, lr, lg,
                    m0);

  // ---- final linear: out[t][0..2], 16 tokens per wave, 4 waves ----
  {
    const int wave = tid >> 6;
    f32x4 acc = {0.f, 0.f, 0.f, 0.f};
#pragma unroll
    for (int ks = 0; ks < 16; ++ks) {
      f16x8 a = *(const f16x8*)&wo[lr * 512 + ks * 32 + lg * 8];
      f16x8 b = *(const f16x8*)&hb[h_elem(ks * 4 + lg, wave * 16 + lr)];
      acc = __builtin_amdgcn_mfma_f32_16x16x32_f16(a, b, acc, 0, 0, 0);
    }
    if (lg == 0) {  // C rows 0..3 in lanes 0..15; out-feature = reg idx
      const int t = t0 + wave * 16 + lr;
      out[t * 3 + 0] = acc[0] + b_out[0];
      out[t * 3 + 1] = acc[1] + b_out[1];
      out[t * 3 + 2] = acc[2] + b_out[2];
    }
  }
}

extern "C" void kernel_launch(void* const* d_in, const int* in_sizes, int n_in,
                              void* d_out, int out_size, void* d_ws,
                              size_t ws_size, hipStream_t stream) {
  const float* coords = (const float*)d_in[0];
  const float* bff    = (const float*)d_in[1];
  const float* Wf     = (const float*)d_in[2];
  const float* bf     = (const float*)d_in[3];
  const float* Wh     = (const float*)d_in[4];
  const float* bh     = (const float*)d_in[5];
  const float* Wo     = (const float*)d_in[6];
  const float* bo     = (const float*)d_in[7];
  float* out = (float*)d_out;

  _Float16* w16 = (_Float16*)d_ws;
  float* biasC = (float*)(w16 + N3);  // 16B-aligned (N3*2 % 16 == 0)

  convert_weights<<<(N3 + NBIAS + 255) / 256, 256, 0, stream>>>(
      Wf, Wh, Wo, bf, bh, w16, biasC);

  const size_t lds_bytes = 64 * 64 * 8 * sizeof(_Float16);  // 65536
  siren_kernel<<<L_TOTAL / TOK, THREADS, lds_bytes, stream>>>(
      coords, bff, biasC, bo, w16, w16 + N1, w16 + N2, out);
}

// Round 6
// 740.303 us; speedup vs baseline: 1.9100x; 1.9100x over previous
//
#include <hip/hip_runtime.h>

// Fused SIREN INR round 6. r3 geometry (TOK=128, 512 thr, 8 waves of
// 64feat x 128tok, chunk-major LDS, 2 barriers/layer) + three a/b-load
// latency attacks:
//  (a) FRAGMENT-ORDERED weights: convert kernel shuffles W into
//      W'[mtile][ks][lane][8] so each a-frag global load is one contiguous
//      1KB burst (r3 scattered 16x64B per instruction).
//  (b) 2-deep a-prefetch (rolling a[3][4]): ~320cyc cover vs ~225cyc L2 hit.
//  (c) b-frag double-buffer (b[2][8]): next k-step's 8 ds_read_b128 issue
//      under the current 32 MFMAs.
// Locked lessons: 1x weight L2 traffic per CU, >=8 MFMA per a-load
// (r2/r4/r5 all ~1.5x slower with 2x traffic / 4:1 ratio).

#define L_TOTAL 262144
#define TOK 128
#define THREADS 512
#define C_SC 4.77464829275686f  // 30/(2*pi)

typedef _Float16 f16x8 __attribute__((ext_vector_type(8)));
typedef _Float16 f16x4 __attribute__((ext_vector_type(4)));
typedef float    f32x4 __attribute__((ext_vector_type(4)));

#define N1 (512 * 256)                 // W_first elems
#define N2 (N1 + 5 * 512 * 512)        // + W_hidden
#define N3 (N2 + 16 * 512)             // + W_out padded to 16 rows
#define NBIAS 3072                     // 512 first + 5*512 hidden (pre-scaled)

// Fragment-ordered destination for first+hidden weights:
// dst[((mt*KS + ks)*64 + lane)*8 + e] = W[row=mt*16+(lane&15)]
//                                        [col=ks*32+(lane>>4)*8+e]
__global__ void convert_weights(const float* __restrict__ Wf,
                                const float* __restrict__ Wh,
                                const float* __restrict__ Wo,
                                const float* __restrict__ bf,
                                const float* __restrict__ bh,
                                _Float16* __restrict__ o,
                                float* __restrict__ biasC) {
  int i = blockIdx.x * blockDim.x + threadIdx.x;
  if (i < N3) {
    float v;
    if (i < N1) {                      // first layer: 512x256, KS=8
      const int blk = i >> 9, w = i & 511;
      const int lane = w >> 3, e = w & 7;
      const int mt = blk >> 3, ks = blk & 7;
      const int row = mt * 16 + (lane & 15);
      const int col = ks * 32 + (lane >> 4) * 8 + e;
      v = Wf[row * 256 + col];
    } else if (i < N2) {               // hidden: 5 x 512x512, KS=16
      int j = i - N1;
      const int l = j >> 18;
      j &= (1 << 18) - 1;
      const int blk = j >> 9, w = j & 511;
      const int lane = w >> 3, e = w & 7;
      const int mt = blk >> 4, ks = blk & 15;
      const int row = mt * 16 + (lane & 15);
      const int col = ks * 32 + (lane >> 4) * 8 + e;
      v = Wh[l * (512 * 512) + row * 512 + col];
    } else {                           // out layer: row-major, padded 16x512
      const int r = (i - N2) >> 9, c = (i - N2) & 511;
      v = (r < 3) ? Wo[r * 512 + c] : 0.0f;
    }
    o[i] = (_Float16)v;
  } else if (i < N3 + NBIAS) {
    int j = i - N3;
    biasC[j] = (j < 512 ? bf[j] : bh[j - 512]) * C_SC;
  }
}

// h LDS layout: elem addr = (chunk*128 + token)*8 + (f&7), chunk = f>>3.
// b-frag ds_read_b128 addr16B = chunk*128 + token: linear in lane ->
// conflict-free.
__device__ __forceinline__ int h_elem(int chunk, int token) {
  return (chunk * 128 + token) * 8;
}

// One sine layer: h <- sin(30*(W h + b)). M=512 (8 waves x 64 feats),
// N=128 tokens (8 ntiles), K templated (256 first / 512 hidden).
// W is fragment-ordered (see convert_weights).
template <int K>
__device__ __forceinline__ void sine_layer(const _Float16* __restrict__ W,
                                           const float* __restrict__ biasC,
                                           _Float16* hb, int lane, int lr,
                                           int lg, int m0) {
  constexpr int KS = K / 32;
  f32x4 acc[4][8];
#pragma unroll
  for (int mt = 0; mt < 4; ++mt)
#pragma unroll
    for (int nt = 0; nt < 8; ++nt)
      acc[mt][nt] = (f32x4){0.f, 0.f, 0.f, 0.f};

  // per-mt fragment-ordered base: one contiguous 1KB burst per (mt, ks)
  const _Float16* wb[4];
#pragma unroll
  for (int mt = 0; mt < 4; ++mt)
    wb[mt] = &W[(((m0 >> 4) + mt) * KS) * 512 + lane * 8];

  f16x8 a[3][4], b[2][8];
#pragma unroll
  for (int mt = 0; mt < 4; ++mt) a[0][mt] = *(const f16x8*)(wb[mt]);
#pragma unroll
  for (int mt = 0; mt < 4; ++mt) a[1][mt] = *(const f16x8*)(wb[mt] + 512);
#pragma unroll
  for (int nt = 0; nt < 8; ++nt)
    b[0][nt] = *(const f16x8*)&hb[h_elem(lg, nt * 16 + lr)];

#pragma unroll
  for (int ks = 0; ks < KS; ++ks) {
    const int cur = ks & 1;
    const int ai = ks % 3;
    if (ks + 1 < KS) {  // prefetch next k-step's b-frags under these MFMAs
#pragma unroll
      for (int nt = 0; nt < 8; ++nt)
        b[cur ^ 1][nt] =
            *(const f16x8*)&hb[h_elem((ks + 1) * 4 + lg, nt * 16 + lr)];
    }
    if (ks + 2 < KS) {  // 2-deep a-prefetch (~320cyc cover)
#pragma unroll
      for (int mt = 0; mt < 4; ++mt)
        a[(ks + 2) % 3][mt] = *(const f16x8*)(wb[mt] + (ks + 2) * 512);
    }
#pragma unroll
    for (int mt = 0; mt < 4; ++mt)
#pragma unroll
      for (int nt = 0; nt < 8; ++nt)
        acc[mt][nt] = __builtin_amdgcn_mfma_f32_16x16x32_f16(
            a[ai][mt], b[cur][nt], acc[mt][nt], 0, 0, 0);
  }
  __syncthreads();  // all reads of hb done before overwrite

#pragma unroll
  for (int mt = 0; mt < 4; ++mt) {
    const int ob = m0 + mt * 16 + lg * 4;  // 4 consecutive out-features
    const f32x4 bb = *(const f32x4*)&biasC[ob];
    const int wbase = (ob >> 3) * 128 * 8 + (ob & 7);
#pragma unroll
    for (int nt = 0; nt < 8; ++nt) {
      f16x4 hv;
#pragma unroll
      for (int r = 0; r < 4; ++r) {
        float pre = fmaf(acc[mt][nt][r], C_SC, bb[r]);  // revolutions
        hv[r] = (_Float16)__builtin_amdgcn_sinf(__builtin_amdgcn_fractf(pre));
      }
      *(f16x4*)&hb[wbase + (nt * 16 + lr) * 8] = hv;
    }
  }
  __syncthreads();
}

__global__ __launch_bounds__(THREADS, 2) void siren_kernel(
    const float* __restrict__ coords, const float* __restrict__ bff,
    const float* __restrict__ biasC, const float* __restrict__ b_out,
    const _Float16* __restrict__ wf, const _Float16* __restrict__ wh,
    const _Float16* __restrict__ wo, float* __restrict__ out) {
  extern __shared__ _Float16 hb[];  // chunk-major: [64 chunks][128 tok][8]
  const int tid = threadIdx.x;
  const int t0 = blockIdx.x * TOK;

  // ---- Fourier features: chunks q*4+cb (sin), 16+q*4+cb (cos) ----
  {
    const int t = tid & 127;   // token (wave = 64 consecutive tokens)
    const int q = tid >> 7;    // feature octant: proj j in [q*32, q*32+32)
    const float c0 = coords[(t0 + t) * 3 + 0];
    const float c1 = coords[(t0 + t) * 3 + 1];
    const float c2 = coords[(t0 + t) * 3 + 2];
#pragma unroll
    for (int cb = 0; cb < 4; ++cb) {
      f16x8 sv, cv;
#pragma unroll
      for (int e = 0; e < 8; ++e) {
        const int j = q * 32 + cb * 8 + e;
        float r = fmaf(c0, bff[j], fmaf(c1, bff[128 + j], c2 * bff[256 + j]));
        float fr = __builtin_amdgcn_fractf(r);
        sv[e] = (_Float16)__builtin_amdgcn_sinf(fr);
        cv[e] = (_Float16)__builtin_amdgcn_cosf(fr);
      }
      *(f16x8*)&hb[h_elem(q * 4 + cb, t)] = sv;        // lane-linear store
      *(f16x8*)&hb[h_elem(16 + q * 4 + cb, t)] = cv;
    }
  }
  __syncthreads();

  const int lane = tid & 63;
  const int lr = lane & 15;   // A: weight row / B: token / C: token col
  const int lg = lane >> 4;   // k-group for frags, row-group for C
  const int m0 = (tid >> 6) * 64;  // wave's 64-feature output slice

  sine_layer<256>(wf, biasC, hb, lane, lr, lg, m0);
#pragma unroll 1
  for (int l = 0; l < 5; ++l)
    sine_layer<512>(wh + l * (512 * 512), biasC + 512 + l * 512, hb, lane, lr,
                    lg, m0);

  // ---- final linear: out[t][0..2], 16 tokens per wave, 8 waves ----
  {
    const int wave = tid >> 6;
    f32x4 acc = {0.f, 0.f, 0.f, 0.f};
#pragma unroll
    for (int ks = 0; ks < 16; ++ks) {
      f16x8 a = *(const f16x8*)&wo[lr * 512 + ks * 32 + lg * 8];
      f16x8 b = *(const f16x8*)&hb[h_elem(ks * 4 + lg, wave * 16 + lr)];
      acc = __builtin_amdgcn_mfma_f32_16x16x32_f16(a, b, acc, 0, 0, 0);
    }
    if (lg == 0) {  // C rows 0..3 in lanes 0..15; out-feature = reg idx
      const int t = t0 + wave * 16 + lr;
      out[t * 3 + 0] = acc[0] + b_out[0];
      out[t * 3 + 1] = acc[1] + b_out[1];
      out[t * 3 + 2] = acc[2] + b_out[2];
    }
  }
}

extern "C" void kernel_launch(void* const* d_in, const int* in_sizes, int n_in,
                              void* d_out, int out_size, void* d_ws,
                              size_t ws_size, hipStream_t stream) {
  const float* coords = (const float*)d_in[0];
  const float* bff    = (const float*)d_in[1];
  const float* Wf     = (const float*)d_in[2];
  const float* bf     = (const float*)d_in[3];
  const float* Wh     = (const float*)d_in[4];
  const float* bh     = (const float*)d_in[5];
  const float* Wo     = (const float*)d_in[6];
  const float* bo     = (const float*)d_in[7];
  float* out = (float*)d_out;

  _Float16* w16 = (_Float16*)d_ws;
  float* biasC = (float*)(w16 + N3);  // 16B-aligned (N3*2 % 16 == 0)

  convert_weights<<<(N3 + NBIAS + 255) / 256, 256, 0, stream>>>(
      Wf, Wh, Wo, bf, bh, w16, biasC);

  const size_t lds_bytes = 64 * 128 * 8 * sizeof(_Float16);  // 131072
  siren_kernel<<<L_TOTAL / TOK, THREADS, lds_bytes, stream>>>(
      coords, bff, biasC, bo, w16, w16 + N1, w16 + N2, out);
}